// Round 3
// baseline (188.530 us; speedup 1.0000x reference)
//
#include <hip/hip_runtime.h>

typedef _Float16 f16x8 __attribute__((ext_vector_type(8)));
typedef _Float16 f16x4t __attribute__((ext_vector_type(4)));
typedef __fp16 h16x2 __attribute__((ext_vector_type(2)));
typedef float f32x4 __attribute__((ext_vector_type(4)));
typedef float f32x16 __attribute__((ext_vector_type(16)));
typedef unsigned int uint2v __attribute__((ext_vector_type(2)));

#define L_SZ 4096

__device__ __forceinline__ unsigned short f2h(float f) {
    _Float16 h = (_Float16)f;
    return __builtin_bit_cast(unsigned short, h);
}
__device__ __forceinline__ unsigned int pk2(float a, float b) {
    h16x2 p = __builtin_amdgcn_cvt_pkrtz(a, b);
    return __builtin_bit_cast(unsigned int, p);
}
// raw v_exp_f32 (no OCML denormal fixup); flush-to-zero below -126 is fine here
__device__ __forceinline__ float fexp2(float x) {
#if __has_builtin(__builtin_amdgcn_exp2f)
    return __builtin_amdgcn_exp2f(x);
#else
    return exp2f(x);
#endif
}
__device__ __forceinline__ float frcp(float x) {
#if __has_builtin(__builtin_amdgcn_rcpf)
    return __builtin_amdgcn_rcpf(x);
#else
    return 1.0f / x;
#endif
}

// LDS slot for 64-row x 8-chunk (16B) K/V tiles: chunk-major, row^chunk xor.
#define SLOT(row, ci) ((((ci) * 64) + ((row) & 32) + (((row) & 31) ^ (ci))) * 8)

// ---------------- K1: QKV projection, split per-projection -----------------
// Grid 768 = tile(256: b x l-tile64) x proj(3). 50KB LDS -> 3 blocks/CU.
// Weights converted fp32->f16 in-block (32 x {float2, pk2, LDS write}).
__global__ __launch_bounds__(256, 3) void qkv_kernel(
    const float* __restrict__ x,
    const float* __restrict__ wq, const float* __restrict__ wk,
    const float* __restrict__ wv,
    const float* __restrict__ bq, const float* __restrict__ bk,
    const float* __restrict__ bv,
    unsigned short* __restrict__ Qp, unsigned short* __restrict__ Kp,
    unsigned short* __restrict__ Vp)
{
    int raw = blockIdx.x;
    int v = (raw & 7) * 96 + (raw >> 3);   // XCD chunk swizzle (768 = 8*96)
    int tile = v / 3;                      // 0..255: same x-tile trio same XCD
    int p = v - tile * 3;                  // 0=Q 1=K 2=V
    int bidx = tile >> 6;
    int l0 = (tile & 63) * 64;
    int tid = threadIdx.x;
    int wave = tid >> 6, lane = tid & 63;
    int c = lane & 15, qd = lane >> 4;

    __shared__ __align__(16) unsigned short Ws[128 * 128]; // 32KB
    __shared__ __align__(16) unsigned short Sc[9216];      // Xs(8192) / Vt(128x72)

    // weights: direct fp32 -> swizzled f16 LDS image
    const float* wsrc = (p == 0) ? wq : (p == 1 ? wk : wv);
    #pragma unroll
    for (int t = 0; t < 32; ++t) {
        int e2 = tid + t * 256;            // 0..8191 float2 elems
        float2 wv2 = *(const float2*)&wsrc[e2 * 2];
        int e = e2 * 2;
        int o = e >> 7, ci = (e & 127) >> 3, j = e & 7;
        *(unsigned int*)&Ws[o * 128 + ((ci ^ (o & 15)) * 8) + j] = pk2(wv2.x, wv2.y);
    }

    // stage x tile into Xs
    unsigned short* Xs = Sc;
    #pragma unroll
    for (int it = 0; it < 8; ++it) {
        int i  = (tid >> 4) + 16 * it;
        int l4 = (tid & 15) * 4;
        const float4 vx = *(const float4*)&x[(bidx * 128 + i) * L_SZ + l0 + l4];
        float vv[4] = {vx.x, vx.y, vx.z, vx.w};
        int ci = i >> 3;
        #pragma unroll
        for (int u = 0; u < 4; ++u) {
            int l = l4 + u;
            Xs[l * 128 + ((ci ^ (l & 15)) * 8) + (i & 7)] = f2h(vv[u]);
        }
    }
    __syncthreads();

    f16x8 afrag[4];
    #pragma unroll
    for (int kc = 0; kc < 4; ++kc) {
        int l = wave * 16 + c;
        int ci = kc * 4 + qd;
        afrag[kc] = *(const f16x8*)&Xs[l * 128 + ((ci ^ (l & 15)) * 8)];
    }
    __syncthreads();   // all Xs reads done before Vt overwrites Sc

    f32x4 acc[8];
    #pragma unroll
    for (int nt = 0; nt < 8; ++nt) acc[nt] = (f32x4){0.f, 0.f, 0.f, 0.f};

    #pragma unroll
    for (int kc = 0; kc < 4; ++kc) {
        #pragma unroll
        for (int nt = 0; nt < 8; ++nt) {
            int o = nt * 16 + c;   // 0..127, o&15 == c
            f16x8 bfrag = *(const f16x8*)&Ws[o * 128 + (((kc * 4 + qd) ^ c) * 8)];
            acc[nt] = __builtin_amdgcn_mfma_f32_16x16x32_f16(afrag[kc], bfrag, acc[nt], 0, 0, 0);
        }
    }

    const float s_q = 0.18033688011f;  // log2(e)/8
    if (p == 0) {
        #pragma unroll
        for (int nt = 0; nt < 8; ++nt) {
            int o = nt * 16 + c;
            int h = o >> 6, d = o & 63;
            #pragma unroll
            for (int r = 0; r < 4; ++r) {
                int l = l0 + wave * 16 + qd * 4 + r;
                Qp[((bidx * 2 + h) * L_SZ + l) * 64 + d] = f2h((acc[nt][r] + bq[o]) * s_q);
            }
        }
    } else if (p == 1) {
        #pragma unroll
        for (int nt = 0; nt < 8; ++nt) {
            int o = nt * 16 + c;
            int h = o >> 6, d = o & 63;
            #pragma unroll
            for (int r = 0; r < 4; ++r) {
                int l = l0 + wave * 16 + qd * 4 + r;
                Kp[((bidx * 2 + h) * L_SZ + l) * 64 + d] = f2h(acc[nt][r] + bk[o]);
            }
        }
    } else {
        unsigned short* Vt = Sc;   // [o][72] pad to break banks
        #pragma unroll
        for (int nt = 0; nt < 8; ++nt) {
            int o = nt * 16 + c;
            #pragma unroll
            for (int r = 0; r < 4; ++r) {
                int ll = wave * 16 + qd * 4 + r;
                Vt[o * 72 + ll] = f2h(acc[nt][r] + bv[o]);
            }
        }
        __syncthreads();
        // cooperative coalesced V store: 128 rows x 64 l
        #pragma unroll
        for (int t = 0; t < 2; ++t) {
            int u = tid + t * 256;          // 0..511
            int row = u >> 2;               // 0..127
            int lc = (u & 3) * 16;          // 16 l (32B) per thread
            uint4 a0 = *(const uint4*)&Vt[row * 72 + lc];
            uint4 a1 = *(const uint4*)&Vt[row * 72 + lc + 8];
            *(uint4*)&Vp[(size_t)(bidx * 128 + row) * L_SZ + l0 + lc] = a0;
            *(uint4*)&Vp[(size_t)(bidx * 128 + row) * L_SZ + l0 + lc + 8] = a1;
        }
    }
}

// ---------------- K2: flash attention -------------------------------------
// Grid 1024 = sp(4) x bh(8) x ltile(32). 4 waves x 32 q-rows.
// 2-deep register prefetch: loads issued at iter i land at bottom of iter i+1
// (one full iteration in flight). Lean softmax (v_exp_f32, max3 tree,
// partial sums, defer-max), in-register P, 4 blocks/CU.
__global__ __launch_bounds__(256, 4) void attn_kernel(
    const unsigned short* __restrict__ Qp, const unsigned short* __restrict__ Kp,
    const unsigned short* __restrict__ Vp,
    unsigned short* __restrict__ Opart, float* __restrict__ Mpart, float* __restrict__ Lpart)
{
    int raw = blockIdx.x;
    int blk = (raw & 7) * 128 + (raw >> 3);   // XCD swizzle: 128-block chunks/XCD
    int lt = blk & 31;
    int bh = (blk >> 5) & 7;
    int sp = blk >> 8;
    int l0 = lt * 128;
    int tid = threadIdx.x;
    int wave = tid >> 6, lane = tid & 63;
    int ln = lane & 31, hi = lane >> 5;
    int b = bh >> 1, h = bh & 1;

    __shared__ __align__(16) unsigned short Ks[2][4096];
    __shared__ __align__(16) unsigned short Vs[2][4096];

    const unsigned short* Qb = Qp + (size_t)bh * L_SZ * 64;
    const unsigned short* Kb = Kp + (size_t)bh * L_SZ * 64;
    const unsigned short* Vb = Vp + ((size_t)b * 128 + h * 64) * L_SZ;

    int lq = l0 + wave * 32 + ln;
    f16x8 qf[4];   // B-operand: n = q-row ln, k chunks
    #pragma unroll
    for (int kc = 0; kc < 4; ++kc)
        qf[kc] = *(const f16x8*)&Qb[(size_t)lq * 64 + kc * 16 + hi * 8];

    float m_st = -1e30f, lsum = 0.f;
    f32x16 acc0 = {}, acc1 = {};

    int urow = tid >> 3, uci = tid & 7;   // staging assignment
    int mglob = sp * 1024;

    uint4 kreg[2][2], vreg[2][2];         // [set][j]

#define LOADT(s, t) do {                                                      \
        int m0_ = mglob + (t) * 64;                                           \
        kreg[s][0] = *(const uint4*)&Kb[(size_t)(m0_ + urow) * 64 + uci * 8]; \
        kreg[s][1] = *(const uint4*)&Kb[(size_t)(m0_ + urow + 32) * 64 + uci * 8]; \
        vreg[s][0] = *(const uint4*)&Vb[(size_t)urow * L_SZ + m0_ + uci * 8]; \
        vreg[s][1] = *(const uint4*)&Vb[(size_t)(urow + 32) * L_SZ + m0_ + uci * 8]; \
    } while (0)
#define STORET(s, buf) do {                                                   \
        *(uint4*)&Ks[buf][SLOT(urow, uci)]      = kreg[s][0];                 \
        *(uint4*)&Ks[buf][SLOT(urow + 32, uci)] = kreg[s][1];                 \
        *(uint4*)&Vs[buf][SLOT(urow, uci)]      = vreg[s][0];                 \
        *(uint4*)&Vs[buf][SLOT(urow + 32, uci)] = vreg[s][1];                 \
    } while (0)

    // prologue: tile0 -> set0 -> LDS0; tile1 -> set1 (in flight across iter 0)
    LOADT(0, 0);
    STORET(0, 0);
    LOADT(1, 1);

    #pragma unroll 2
    for (int it = 0; it < 16; ++it) {
        int cur = it & 1;
        __syncthreads();                       // LDS[cur] = tile it ready
        if (it < 14) {                         // issue tile it+2 into freed set
            LOADT(it & 1, it + 2);
        }

        __builtin_amdgcn_s_setprio(1);
        // S^T = K . Q^T
        f32x16 s0 = {}, s1 = {};
        #pragma unroll
        for (int kc = 0; kc < 4; ++kc) {
            int cd = kc * 2 + hi;
            f16x8 k0 = *(const f16x8*)&Ks[cur][SLOT(ln, cd)];
            f16x8 k1 = *(const f16x8*)&Ks[cur][SLOT(32 + ln, cd)];
            s0 = __builtin_amdgcn_mfma_f32_32x32x16_f16(k0, qf[kc], s0, 0, 0, 0);
            s1 = __builtin_amdgcn_mfma_f32_32x32x16_f16(k1, qf[kc], s1, 0, 0, 0);
        }

        // max3-shaped tree
        float t[8];
        #pragma unroll
        for (int r = 0; r < 8; ++r)
            t[r] = fmaxf(fmaxf(s0[r], s0[r + 8]), s1[r]);
        #pragma unroll
        for (int r = 0; r < 4; ++r)
            t[r] = fmaxf(fmaxf(t[r], t[r + 4]), s1[8 + r]);
        float m01 = fmaxf(fmaxf(t[0], t[1]), s1[12]);
        float m23 = fmaxf(fmaxf(t[2], t[3]), s1[13]);
        float mx = fmaxf(fmaxf(m01, m23), fmaxf(s1[14], s1[15]));
        mx = fmaxf(mx, __shfl_xor(mx, 32));

        // defer-max: only rescale when max grew past threshold (base-2 units).
        if (!__all(mx <= m_st + 8.0f)) {
            float mnew = fmaxf(m_st, mx);
            float alpha = fexp2(m_st - mnew);
            m_st = mnew;
            lsum *= alpha;
            #pragma unroll
            for (int r = 0; r < 16; ++r) { acc0[r] *= alpha; acc1[r] *= alpha; }
        }
        // raw v_exp_f32; 4-way partial sums
        float rs0 = 0.f, rs1 = 0.f, rs2 = 0.f, rs3 = 0.f;
        #pragma unroll
        for (int r = 0; r < 4; ++r) {
            float p0 = fexp2(s0[r]      - m_st); s0[r]      = p0; rs0 += p0;
            float p1 = fexp2(s0[r + 4]  - m_st); s0[r + 4]  = p1; rs1 += p1;
            float p2 = fexp2(s0[r + 8]  - m_st); s0[r + 8]  = p2; rs2 += p2;
            float p3 = fexp2(s0[r + 12] - m_st); s0[r + 12] = p3; rs3 += p3;
        }
        #pragma unroll
        for (int r = 0; r < 4; ++r) {
            float p0 = fexp2(s1[r]      - m_st); s1[r]      = p0; rs0 += p0;
            float p1 = fexp2(s1[r + 4]  - m_st); s1[r + 4]  = p1; rs1 += p1;
            float p2 = fexp2(s1[r + 8]  - m_st); s1[r + 8]  = p2; rs2 += p2;
            float p3 = fexp2(s1[r + 12] - m_st); s1[r + 12] = p3; rs3 += p3;
        }
        lsum += (rs0 + rs1) + (rs2 + rs3);

        // O^T += V . P^T, P^T B-frag assembled in-register
        #pragma unroll
        for (int kc = 0; kc < 4; ++kc) {
            unsigned int a0, a1, a2, a3;
            if (kc == 0) {
                a0 = pk2(s0[0], s0[1]);  a1 = pk2(s0[2], s0[3]);
                a2 = pk2(s0[4], s0[5]);  a3 = pk2(s0[6], s0[7]);
            } else if (kc == 1) {
                a0 = pk2(s0[8], s0[9]);  a1 = pk2(s0[10], s0[11]);
                a2 = pk2(s0[12], s0[13]); a3 = pk2(s0[14], s0[15]);
            } else if (kc == 2) {
                a0 = pk2(s1[0], s1[1]);  a1 = pk2(s1[2], s1[3]);
                a2 = pk2(s1[4], s1[5]);  a3 = pk2(s1[6], s1[7]);
            } else {
                a0 = pk2(s1[8], s1[9]);  a1 = pk2(s1[10], s1[11]);
                a2 = pk2(s1[12], s1[13]); a3 = pk2(s1[14], s1[15]);
            }
            uint2v r02 = __builtin_amdgcn_permlane32_swap(a0, a2, false, false);
            uint2v r13 = __builtin_amdgcn_permlane32_swap(a1, a3, false, false);
            uint4 pw; pw.x = r02[0]; pw.y = r13[0]; pw.z = r02[1]; pw.w = r13[1];
            f16x8 pf = __builtin_bit_cast(f16x8, pw);
            int cd = kc * 2 + hi;
            f16x8 v0 = *(const f16x8*)&Vs[cur][SLOT(ln, cd)];
            f16x8 v1 = *(const f16x8*)&Vs[cur][SLOT(32 + ln, cd)];
            acc0 = __builtin_amdgcn_mfma_f32_32x32x16_f16(v0, pf, acc0, 0, 0, 0);
            acc1 = __builtin_amdgcn_mfma_f32_32x32x16_f16(v1, pf, acc1, 0, 0, 0);
        }
        __builtin_amdgcn_s_setprio(0);

        if (it < 15) {                         // stage tile it+1 (loaded last iter)
            STORET((it + 1) & 1, cur ^ 1);
        }
    }
#undef LOADT
#undef STORET

    float l_tot = lsum + __shfl_xor(lsum, 32);
    unsigned short* Ow = Opart + (size_t)(sp * 8 + bh) * 64 * 4096;
    #pragma unroll
    for (int r = 0; r < 16; ++r) {
        int d0 = (r & 3) + 8 * (r >> 2) + 4 * hi;
        Ow[(size_t)d0 * 4096 + lq] = f2h(acc0[r]);
        Ow[(size_t)(32 + d0) * 4096 + lq] = f2h(acc1[r]);
    }
    if (hi == 0) {
        Mpart[(sp * 8 + bh) * 4096 + lq] = m_st;
        Lpart[(sp * 8 + bh) * 4096 + lq] = l_tot;
    }
}

// ---------------- K3: combine + fc + BN + PReLU ----------------------------
// Grid 512 = 32-row blocks (one (b,c) pair each) -> 2 blocks/CU.
// fcw converted in-block; hoisted Opart gathers; BN params block-constant.
__global__ __launch_bounds__(256, 2) void fc_kernel(
    const unsigned short* __restrict__ Opart, const float* __restrict__ Mp,
    const float* __restrict__ Lp, const float* __restrict__ fcw_f,
    const float* __restrict__ fc_b, const float* __restrict__ bn_g,
    const float* __restrict__ bn_b, const float* __restrict__ bn_m,
    const float* __restrict__ bn_v, const float* __restrict__ prelu_a,
    float* __restrict__ out)
{
    int raw = blockIdx.x;
    int blk = (raw & 7) * 64 + (raw >> 3);    // 64-block chunks/XCD == one bh
    int r0 = blk * 32;
    int tid = threadIdx.x;
    int c0 = blk & 127;                        // channel (block-constant)
    int bh = blk >> 6;
    int d = c0 & 63;

    int wave = tid >> 6, lane = tid & 63;
    int c = lane & 15, qd = lane >> 4;
    int rw = r0 + (wave >> 1) * 16;
    int o0 = (wave & 1) * 64;
    int hh = (rw + c) & 31;                    // = (wave>>1)*16 + c

    __shared__ __align__(16) unsigned short Fw[128 * 128];   // 32KB
    __shared__ __align__(16) unsigned short SclU[4096 * 4];  // 32KB

    // hoisted Opart gathers (independent of LDS)
    uint4 ovr[4][4];
    #pragma unroll
    for (int kc = 0; kc < 4; ++kc) {
        int w0 = kc * 32 + qd * 8;
        #pragma unroll
        for (int s = 0; s < 4; ++s)
            ovr[kc][s] = *(const uint4*)&Opart[(size_t)(s * 8 + bh) * 262144 + (size_t)d * 4096 + hh * 128 + w0];
    }

    // scales: slot(l) = h*128 + ((w + h)&127)
    #pragma unroll
    for (int t = 0; t < 16; ++t) {
        int l = tid + t * 256;
        float m0 = Mp[(0 * 8 + bh) * 4096 + l], m1 = Mp[(1 * 8 + bh) * 4096 + l];
        float m2 = Mp[(2 * 8 + bh) * 4096 + l], m3 = Mp[(3 * 8 + bh) * 4096 + l];
        float mx = fmaxf(fmaxf(m0, m1), fmaxf(m2, m3));
        float a0 = fexp2(m0 - mx), a1 = fexp2(m1 - mx);
        float a2 = fexp2(m2 - mx), a3 = fexp2(m3 - mx);
        float den = a0 * Lp[(0 * 8 + bh) * 4096 + l] + a1 * Lp[(1 * 8 + bh) * 4096 + l]
                  + a2 * Lp[(2 * 8 + bh) * 4096 + l] + a3 * Lp[(3 * 8 + bh) * 4096 + l];
        float inv = frcp(den);
        int hl = l >> 7, ww = l & 127;
        int slot = hl * 128 + ((ww + hl) & 127);
        uint2 sc;
        sc.x = pk2(a0 * inv, a1 * inv);
        sc.y = pk2(a2 * inv, a3 * inv);
        *(uint2*)&SclU[slot * 4] = sc;
    }
    // fcw: direct fp32 -> swizzled f16 LDS image
    #pragma unroll
    for (int t = 0; t < 32; ++t) {
        int e2 = tid + t * 256;            // 0..8191 float2 elems
        float2 v = *(const float2*)&fcw_f[e2 * 2];
        int e = e2 * 2;
        int o = e >> 7, ci = (e & 127) >> 3, j = e & 7;
        *(unsigned int*)&Fw[o * 128 + ((ci ^ (o & 15)) * 8) + j] = pk2(v.x, v.y);
    }
    __syncthreads();

    // A-frags: combine 4 splits with scales (from hoisted regs)
    f16x8 af[4];
    #pragma unroll
    for (int kc = 0; kc < 4; ++kc) {
        int w0 = kc * 32 + qd * 8;
        f16x8 ov0 = __builtin_bit_cast(f16x8, ovr[kc][0]);
        f16x8 ov1 = __builtin_bit_cast(f16x8, ovr[kc][1]);
        f16x8 ov2 = __builtin_bit_cast(f16x8, ovr[kc][2]);
        f16x8 ov3 = __builtin_bit_cast(f16x8, ovr[kc][3]);
        #pragma unroll
        for (int j = 0; j < 8; ++j) {
            int slot = hh * 128 + ((w0 + j + hh) & 127);
            f16x4t sc = *(const f16x4t*)&SclU[slot * 4];
            float v = (float)ov0[j] * (float)sc[0] + (float)ov1[j] * (float)sc[1]
                    + (float)ov2[j] * (float)sc[2] + (float)ov3[j] * (float)sc[3];
            af[kc][j] = (_Float16)v;
        }
    }

    f32x4 acc[4];
    #pragma unroll
    for (int nt = 0; nt < 4; ++nt) acc[nt] = (f32x4){0.f, 0.f, 0.f, 0.f};
    #pragma unroll
    for (int kc = 0; kc < 4; ++kc) {
        #pragma unroll
        for (int nt = 0; nt < 4; ++nt) {
            int o = o0 + nt * 16 + c;
            f16x8 bf = *(const f16x8*)&Fw[o * 128 + (((kc * 4 + qd) ^ c) * 8)];
            acc[nt] = __builtin_amdgcn_mfma_f32_16x16x32_f16(af[kc], bf, acc[nt], 0, 0, 0);
        }
    }

    float pa = prelu_a[0];
    float g  = bn_g[c0] * rsqrtf(bn_v[c0] + 1e-5f);
    float mn = bn_m[c0], bt = bn_b[c0];
    #pragma unroll
    for (int r = 0; r < 4; ++r) {
        int orow = rw + qd * 4 + r;
        #pragma unroll
        for (int nt = 0; nt < 4; ++nt) {
            int o = o0 + nt * 16 + c;
            float y = (acc[nt][r] + fc_b[o] - mn) * g + bt;
            y = y > 0.f ? y : pa * y;
            out[(size_t)orow * 128 + o] = y;
        }
    }
}

extern "C" void kernel_launch(void* const* d_in, const int* in_sizes, int n_in,
                              void* d_out, int out_size, void* d_ws, size_t ws_size,
                              hipStream_t stream) {
    const float* x     = (const float*)d_in[0];
    const float* wq    = (const float*)d_in[1];
    const float* bq    = (const float*)d_in[2];
    const float* wk    = (const float*)d_in[3];
    const float* bk    = (const float*)d_in[4];
    const float* wv    = (const float*)d_in[5];
    const float* bv    = (const float*)d_in[6];
    const float* fcw_f = (const float*)d_in[7];
    const float* fcb   = (const float*)d_in[8];
    const float* bn_g  = (const float*)d_in[9];
    const float* bn_b  = (const float*)d_in[10];
    const float* bn_m  = (const float*)d_in[11];
    const float* bn_v  = (const float*)d_in[12];
    const float* pa    = (const float*)d_in[13];
    float* out = (float*)d_out;

    unsigned short* Qp  = (unsigned short*)d_ws;
    unsigned short* Kp  = Qp + 8 * L_SZ * 64;
    unsigned short* Vp  = Kp + 8 * L_SZ * 64;
    unsigned short* Opart = Vp + 8 * L_SZ * 64;   // f16, 4*8*64*4096
    float* Mpart = (float*)(Opart + 4 * 8 * 64 * L_SZ);
    float* Lpart = Mpart + 4 * 8 * L_SZ;

    hipLaunchKernelGGL(qkv_kernel,  dim3(768),  dim3(256), 0, stream,
                       x, wq, wk, wv, bq, bk, bv, Qp, Kp, Vp);
    hipLaunchKernelGGL(attn_kernel, dim3(1024), dim3(256), 0, stream,
                       Qp, Kp, Vp, Opart, Mpart, Lpart);
    hipLaunchKernelGGL(fc_kernel,   dim3(512),  dim3(256), 0, stream,
                       Opart, Mpart, Lpart, fcw_f, fcb, bn_g, bn_b, bn_m, bn_v, pa, out);
}

// Round 5
// 157.061 us; speedup vs baseline: 1.2004x; 1.2004x over previous
//
#include <hip/hip_runtime.h>

typedef _Float16 f16x8 __attribute__((ext_vector_type(8)));
typedef _Float16 f16x4t __attribute__((ext_vector_type(4)));
typedef __fp16 h16x2 __attribute__((ext_vector_type(2)));
typedef float f32x4 __attribute__((ext_vector_type(4)));
typedef float f32x16 __attribute__((ext_vector_type(16)));
typedef unsigned int uint2v __attribute__((ext_vector_type(2)));

#define L_SZ 4096

__device__ __forceinline__ unsigned short f2h(float f) {
    _Float16 h = (_Float16)f;
    return __builtin_bit_cast(unsigned short, h);
}
__device__ __forceinline__ unsigned int pk2(float a, float b) {
    h16x2 p = __builtin_amdgcn_cvt_pkrtz(a, b);
    return __builtin_bit_cast(unsigned int, p);
}
// raw v_exp_f32 (no OCML denormal fixup); flush-to-zero below -126 is fine here
__device__ __forceinline__ float fexp2(float x) {
#if __has_builtin(__builtin_amdgcn_exp2f)
    return __builtin_amdgcn_exp2f(x);
#else
    return exp2f(x);
#endif
}
__device__ __forceinline__ float frcp(float x) {
#if __has_builtin(__builtin_amdgcn_rcpf)
    return __builtin_amdgcn_rcpf(x);
#else
    return 1.0f / x;
#endif
}
// async global->LDS DMA, 16B per lane; lds must be wave-uniform, dest = lds + lane*16
__device__ __forceinline__ void async16(unsigned short* lds, const unsigned short* g) {
    __builtin_amdgcn_global_load_lds(
        (const __attribute__((address_space(1))) unsigned int*)g,
        (__attribute__((address_space(3))) unsigned int*)lds, 16, 0, 0);
}

// LDS slot for 64-row x 8-chunk (16B) K/V tiles: chunk-major, row^chunk xor.
#define SLOT(row, ci) ((((ci) * 64) + ((row) & 32) + (((row) & 31) ^ (ci))) * 8)

// ---------------- K1: QKV projection, split per-projection -----------------
// Grid 768 = tile(256: b x l-tile64) x proj(3). 50KB LDS -> 3 blocks/CU.
__global__ __launch_bounds__(256, 3) void qkv_kernel(
    const float* __restrict__ x,
    const float* __restrict__ wq, const float* __restrict__ wk,
    const float* __restrict__ wv,
    const float* __restrict__ bq, const float* __restrict__ bk,
    const float* __restrict__ bv,
    unsigned short* __restrict__ Qp, unsigned short* __restrict__ Kp,
    unsigned short* __restrict__ Vp)
{
    int raw = blockIdx.x;
    int v = (raw & 7) * 96 + (raw >> 3);   // XCD chunk swizzle (768 = 8*96)
    int tile = v / 3;                      // 0..255: same x-tile trio same XCD
    int p = v - tile * 3;                  // 0=Q 1=K 2=V
    int bidx = tile >> 6;
    int l0 = (tile & 63) * 64;
    int tid = threadIdx.x;
    int wave = tid >> 6, lane = tid & 63;
    int c = lane & 15, qd = lane >> 4;

    __shared__ __align__(16) unsigned short Ws[128 * 128]; // 32KB
    __shared__ __align__(16) unsigned short Sc[9216];      // Xs(8192) / Vt(128x72)

    // weights: direct fp32 -> swizzled f16 LDS image
    const float* wsrc = (p == 0) ? wq : (p == 1 ? wk : wv);
    #pragma unroll
    for (int t = 0; t < 32; ++t) {
        int e2 = tid + t * 256;            // 0..8191 float2 elems
        float2 wv2 = *(const float2*)&wsrc[e2 * 2];
        int e = e2 * 2;
        int o = e >> 7, ci = (e & 127) >> 3, j = e & 7;
        *(unsigned int*)&Ws[o * 128 + ((ci ^ (o & 15)) * 8) + j] = pk2(wv2.x, wv2.y);
    }

    // stage x tile into Xs
    unsigned short* Xs = Sc;
    #pragma unroll
    for (int it = 0; it < 8; ++it) {
        int i  = (tid >> 4) + 16 * it;
        int l4 = (tid & 15) * 4;
        const float4 vx = *(const float4*)&x[(bidx * 128 + i) * L_SZ + l0 + l4];
        float vv[4] = {vx.x, vx.y, vx.z, vx.w};
        int ci = i >> 3;
        #pragma unroll
        for (int u = 0; u < 4; ++u) {
            int l = l4 + u;
            Xs[l * 128 + ((ci ^ (l & 15)) * 8) + (i & 7)] = f2h(vv[u]);
        }
    }
    __syncthreads();

    f16x8 afrag[4];
    #pragma unroll
    for (int kc = 0; kc < 4; ++kc) {
        int l = wave * 16 + c;
        int ci = kc * 4 + qd;
        afrag[kc] = *(const f16x8*)&Xs[l * 128 + ((ci ^ (l & 15)) * 8)];
    }
    __syncthreads();   // all Xs reads done before Vt overwrites Sc

    f32x4 acc[8];
    #pragma unroll
    for (int nt = 0; nt < 8; ++nt) acc[nt] = (f32x4){0.f, 0.f, 0.f, 0.f};

    #pragma unroll
    for (int kc = 0; kc < 4; ++kc) {
        #pragma unroll
        for (int nt = 0; nt < 8; ++nt) {
            int o = nt * 16 + c;   // 0..127, o&15 == c
            f16x8 bfrag = *(const f16x8*)&Ws[o * 128 + (((kc * 4 + qd) ^ c) * 8)];
            acc[nt] = __builtin_amdgcn_mfma_f32_16x16x32_f16(afrag[kc], bfrag, acc[nt], 0, 0, 0);
        }
    }

    const float s_q = 0.18033688011f;  // log2(e)/8
    if (p == 0) {
        #pragma unroll
        for (int nt = 0; nt < 8; ++nt) {
            int o = nt * 16 + c;
            int h = o >> 6, d = o & 63;
            #pragma unroll
            for (int r = 0; r < 4; ++r) {
                int l = l0 + wave * 16 + qd * 4 + r;
                Qp[((bidx * 2 + h) * L_SZ + l) * 64 + d] = f2h((acc[nt][r] + bq[o]) * s_q);
            }
        }
    } else if (p == 1) {
        #pragma unroll
        for (int nt = 0; nt < 8; ++nt) {
            int o = nt * 16 + c;
            int h = o >> 6, d = o & 63;
            #pragma unroll
            for (int r = 0; r < 4; ++r) {
                int l = l0 + wave * 16 + qd * 4 + r;
                Kp[((bidx * 2 + h) * L_SZ + l) * 64 + d] = f2h(acc[nt][r] + bk[o]);
            }
        }
    } else {
        unsigned short* Vt = Sc;   // [o][72] pad to break banks
        #pragma unroll
        for (int nt = 0; nt < 8; ++nt) {
            int o = nt * 16 + c;
            #pragma unroll
            for (int r = 0; r < 4; ++r) {
                int ll = wave * 16 + qd * 4 + r;
                Vt[o * 72 + ll] = f2h(acc[nt][r] + bv[o]);
            }
        }
        __syncthreads();
        // cooperative coalesced V store: 128 rows x 64 l
        #pragma unroll
        for (int t = 0; t < 2; ++t) {
            int u = tid + t * 256;          // 0..511
            int row = u >> 2;               // 0..127
            int lc = (u & 3) * 16;          // 16 l (32B) per thread
            uint4 a0 = *(const uint4*)&Vt[row * 72 + lc];
            uint4 a1 = *(const uint4*)&Vt[row * 72 + lc + 8];
            *(uint4*)&Vp[(size_t)(bidx * 128 + row) * L_SZ + l0 + lc] = a0;
            *(uint4*)&Vp[(size_t)(bidx * 128 + row) * L_SZ + l0 + lc + 8] = a1;
        }
    }
}

// ---------------- K2: flash attention -------------------------------------
// Grid 1024 = sp(4) x bh(8) x ltile(32). 4 waves x 32 q-rows.
// Zero-register staging: global_load_lds DMA with inverse-swizzled global
// source (rule #21: linear LDS dest + pre-swizzled src + SLOT on read).
// Lean softmax (v_exp_f32, max3 tree, partial sums, defer-max), in-reg P.
__global__ __launch_bounds__(256, 4) void attn_kernel(
    const unsigned short* __restrict__ Qp, const unsigned short* __restrict__ Kp,
    const unsigned short* __restrict__ Vp,
    unsigned short* __restrict__ Opart, float* __restrict__ Mpart, float* __restrict__ Lpart)
{
    int raw = blockIdx.x;
    int blk = (raw & 7) * 128 + (raw >> 3);   // XCD swizzle: 128-block chunks/XCD
    int lt = blk & 31;
    int bh = (blk >> 5) & 7;
    int sp = blk >> 8;
    int l0 = lt * 128;
    int tid = threadIdx.x;
    int wave = tid >> 6, lane = tid & 63;
    int ln = lane & 31, hi = lane >> 5;
    int b = bh >> 1, h = bh & 1;

    __shared__ __align__(16) unsigned short Ks[2][4096];
    __shared__ __align__(16) unsigned short Vs[2][4096];

    const unsigned short* Qb = Qp + (size_t)bh * L_SZ * 64;
    const unsigned short* Kb = Kp + (size_t)bh * L_SZ * 64;
    const unsigned short* Vb = Vp + ((size_t)b * 128 + h * 64) * L_SZ;

    int lq = l0 + wave * 32 + ln;
    f16x8 qf[4];   // B-operand: n = q-row ln, k chunks
    #pragma unroll
    for (int kc = 0; kc < 4; ++kc)
        qf[kc] = *(const f16x8*)&Qb[(size_t)lq * 64 + kc * 16 + hi * 8];

    float m_st = -1e30f, lsum = 0.f;
    f32x16 acc0 = {}, acc1 = {};

    int mglob = sp * 1024;
    // DMA lane geometry: call (j,wave) covers slots u = j*256 + wave*64 + lane.
    // ci = j*4 + wave (wave-uniform), row = (lane&32)|((lane&31)^ci);
    // then slot u == SLOT(row,ci)/8 exactly -> linear LDS dest, SLOT reads OK.
    int ci0 = wave, ci1 = 4 + wave;
    int r0_ = (lane & 32) | ((lane & 31) ^ ci0);
    int r1_ = (lane & 32) | ((lane & 31) ^ ci1);

#define STAGE(t, buf) do {                                                        \
        int m0_ = mglob + (t) * 64;                                               \
        async16(&Ks[buf][(wave * 64) * 8],       &Kb[(size_t)(m0_ + r0_) * 64 + ci0 * 8]); \
        async16(&Ks[buf][(256 + wave * 64) * 8], &Kb[(size_t)(m0_ + r1_) * 64 + ci1 * 8]); \
        async16(&Vs[buf][(wave * 64) * 8],       &Vb[(size_t)r0_ * L_SZ + m0_ + ci0 * 8]); \
        async16(&Vs[buf][(256 + wave * 64) * 8], &Vb[(size_t)r1_ * L_SZ + m0_ + ci1 * 8]); \
    } while (0)

    STAGE(0, 0);                               // tile 0 in flight

    for (int it = 0; it < 16; ++it) {
        int cur = it & 1;
        __syncthreads();                       // vmcnt(0)+barrier: tile it landed
        if (it < 15) STAGE(it + 1, cur ^ 1);   // DMA next tile; lands by next barrier

        __builtin_amdgcn_s_setprio(1);
        // S^T = K . Q^T
        f32x16 s0 = {}, s1 = {};
        #pragma unroll
        for (int kc = 0; kc < 4; ++kc) {
            int cd = kc * 2 + hi;
            f16x8 k0 = *(const f16x8*)&Ks[cur][SLOT(ln, cd)];
            f16x8 k1 = *(const f16x8*)&Ks[cur][SLOT(32 + ln, cd)];
            s0 = __builtin_amdgcn_mfma_f32_32x32x16_f16(k0, qf[kc], s0, 0, 0, 0);
            s1 = __builtin_amdgcn_mfma_f32_32x32x16_f16(k1, qf[kc], s1, 0, 0, 0);
        }

        // max3-shaped tree
        float t[8];
        #pragma unroll
        for (int r = 0; r < 8; ++r)
            t[r] = fmaxf(fmaxf(s0[r], s0[r + 8]), s1[r]);
        #pragma unroll
        for (int r = 0; r < 4; ++r)
            t[r] = fmaxf(fmaxf(t[r], t[r + 4]), s1[8 + r]);
        float m01 = fmaxf(fmaxf(t[0], t[1]), s1[12]);
        float m23 = fmaxf(fmaxf(t[2], t[3]), s1[13]);
        float mx = fmaxf(fmaxf(m01, m23), fmaxf(s1[14], s1[15]));
        mx = fmaxf(mx, __shfl_xor(mx, 32));

        // defer-max: only rescale when max grew past threshold (base-2 units).
        if (!__all(mx <= m_st + 8.0f)) {
            float mnew = fmaxf(m_st, mx);
            float alpha = fexp2(m_st - mnew);
            m_st = mnew;
            lsum *= alpha;
            #pragma unroll
            for (int r = 0; r < 16; ++r) { acc0[r] *= alpha; acc1[r] *= alpha; }
        }
        // raw v_exp_f32; 4-way partial sums
        float rs0 = 0.f, rs1 = 0.f, rs2 = 0.f, rs3 = 0.f;
        #pragma unroll
        for (int r = 0; r < 4; ++r) {
            float p0 = fexp2(s0[r]      - m_st); s0[r]      = p0; rs0 += p0;
            float p1 = fexp2(s0[r + 4]  - m_st); s0[r + 4]  = p1; rs1 += p1;
            float p2 = fexp2(s0[r + 8]  - m_st); s0[r + 8]  = p2; rs2 += p2;
            float p3 = fexp2(s0[r + 12] - m_st); s0[r + 12] = p3; rs3 += p3;
        }
        #pragma unroll
        for (int r = 0; r < 4; ++r) {
            float p0 = fexp2(s1[r]      - m_st); s1[r]      = p0; rs0 += p0;
            float p1 = fexp2(s1[r + 4]  - m_st); s1[r + 4]  = p1; rs1 += p1;
            float p2 = fexp2(s1[r + 8]  - m_st); s1[r + 8]  = p2; rs2 += p2;
            float p3 = fexp2(s1[r + 12] - m_st); s1[r + 12] = p3; rs3 += p3;
        }
        lsum += (rs0 + rs1) + (rs2 + rs3);

        // O^T += V . P^T, P^T B-frag assembled in-register
        #pragma unroll
        for (int kc = 0; kc < 4; ++kc) {
            unsigned int a0, a1, a2, a3;
            if (kc == 0) {
                a0 = pk2(s0[0], s0[1]);  a1 = pk2(s0[2], s0[3]);
                a2 = pk2(s0[4], s0[5]);  a3 = pk2(s0[6], s0[7]);
            } else if (kc == 1) {
                a0 = pk2(s0[8], s0[9]);  a1 = pk2(s0[10], s0[11]);
                a2 = pk2(s0[12], s0[13]); a3 = pk2(s0[14], s0[15]);
            } else if (kc == 2) {
                a0 = pk2(s1[0], s1[1]);  a1 = pk2(s1[2], s1[3]);
                a2 = pk2(s1[4], s1[5]);  a3 = pk2(s1[6], s1[7]);
            } else {
                a0 = pk2(s1[8], s1[9]);  a1 = pk2(s1[10], s1[11]);
                a2 = pk2(s1[12], s1[13]); a3 = pk2(s1[14], s1[15]);
            }
            uint2v r02 = __builtin_amdgcn_permlane32_swap(a0, a2, false, false);
            uint2v r13 = __builtin_amdgcn_permlane32_swap(a1, a3, false, false);
            uint4 pw; pw.x = r02[0]; pw.y = r13[0]; pw.z = r02[1]; pw.w = r13[1];
            f16x8 pf = __builtin_bit_cast(f16x8, pw);
            int cd = kc * 2 + hi;
            f16x8 v0 = *(const f16x8*)&Vs[cur][SLOT(ln, cd)];
            f16x8 v1 = *(const f16x8*)&Vs[cur][SLOT(32 + ln, cd)];
            acc0 = __builtin_amdgcn_mfma_f32_32x32x16_f16(v0, pf, acc0, 0, 0, 0);
            acc1 = __builtin_amdgcn_mfma_f32_32x32x16_f16(v1, pf, acc1, 0, 0, 0);
        }
        __builtin_amdgcn_s_setprio(0);
    }
#undef STAGE

    float l_tot = lsum + __shfl_xor(lsum, 32);
    unsigned short* Ow = Opart + (size_t)(sp * 8 + bh) * 64 * 4096;
    #pragma unroll
    for (int r = 0; r < 16; ++r) {
        int d0 = (r & 3) + 8 * (r >> 2) + 4 * hi;
        Ow[(size_t)d0 * 4096 + lq] = f2h(acc0[r]);
        Ow[(size_t)(32 + d0) * 4096 + lq] = f2h(acc1[r]);
    }
    if (hi == 0) {
        Mpart[(sp * 8 + bh) * 4096 + lq] = m_st;
        Lpart[(sp * 8 + bh) * 4096 + lq] = l_tot;
    }
}

// ---------------- K3: combine + fc + BN + PReLU ----------------------------
// Grid 512 = 32-row blocks (one (b,c) pair each) -> 2 blocks/CU.
__global__ __launch_bounds__(256, 2) void fc_kernel(
    const unsigned short* __restrict__ Opart, const float* __restrict__ Mp,
    const float* __restrict__ Lp, const float* __restrict__ fcw_f,
    const float* __restrict__ fc_b, const float* __restrict__ bn_g,
    const float* __restrict__ bn_b, const float* __restrict__ bn_m,
    const float* __restrict__ bn_v, const float* __restrict__ prelu_a,
    float* __restrict__ out)
{
    int raw = blockIdx.x;
    int blk = (raw & 7) * 64 + (raw >> 3);    // 64-block chunks/XCD == one bh
    int r0 = blk * 32;
    int tid = threadIdx.x;
    int c0 = blk & 127;                        // channel (block-constant)
    int bh = blk >> 6;
    int d = c0 & 63;

    int wave = tid >> 6, lane = tid & 63;
    int c = lane & 15, qd = lane >> 4;
    int rw = r0 + (wave >> 1) * 16;
    int o0 = (wave & 1) * 64;
    int hh = (rw + c) & 31;                    // = (wave>>1)*16 + c

    __shared__ __align__(16) unsigned short Fw[128 * 128];   // 32KB
    __shared__ __align__(16) unsigned short SclU[4096 * 4];  // 32KB

    // hoisted Opart gathers (independent of LDS)
    uint4 ovr[4][4];
    #pragma unroll
    for (int kc = 0; kc < 4; ++kc) {
        int w0 = kc * 32 + qd * 8;
        #pragma unroll
        for (int s = 0; s < 4; ++s)
            ovr[kc][s] = *(const uint4*)&Opart[(size_t)(s * 8 + bh) * 262144 + (size_t)d * 4096 + hh * 128 + w0];
    }

    // scales: slot(l) = h*128 + ((w + h)&127)
    #pragma unroll
    for (int t = 0; t < 16; ++t) {
        int l = tid + t * 256;
        float m0 = Mp[(0 * 8 + bh) * 4096 + l], m1 = Mp[(1 * 8 + bh) * 4096 + l];
        float m2 = Mp[(2 * 8 + bh) * 4096 + l], m3 = Mp[(3 * 8 + bh) * 4096 + l];
        float mx = fmaxf(fmaxf(m0, m1), fmaxf(m2, m3));
        float a0 = fexp2(m0 - mx), a1 = fexp2(m1 - mx);
        float a2 = fexp2(m2 - mx), a3 = fexp2(m3 - mx);
        float den = a0 * Lp[(0 * 8 + bh) * 4096 + l] + a1 * Lp[(1 * 8 + bh) * 4096 + l]
                  + a2 * Lp[(2 * 8 + bh) * 4096 + l] + a3 * Lp[(3 * 8 + bh) * 4096 + l];
        float inv = frcp(den);
        int hl = l >> 7, ww = l & 127;
        int slot = hl * 128 + ((ww + hl) & 127);
        uint2 sc;
        sc.x = pk2(a0 * inv, a1 * inv);
        sc.y = pk2(a2 * inv, a3 * inv);
        *(uint2*)&SclU[slot * 4] = sc;
    }
    // fcw: direct fp32 -> swizzled f16 LDS image
    #pragma unroll
    for (int t = 0; t < 32; ++t) {
        int e2 = tid + t * 256;            // 0..8191 float2 elems
        float2 v = *(const float2*)&fcw_f[e2 * 2];
        int e = e2 * 2;
        int o = e >> 7, ci = (e & 127) >> 3, j = e & 7;
        *(unsigned int*)&Fw[o * 128 + ((ci ^ (o & 15)) * 8) + j] = pk2(v.x, v.y);
    }
    __syncthreads();

    // A-frags: combine 4 splits with scales (from hoisted regs)
    f16x8 af[4];
    #pragma unroll
    for (int kc = 0; kc < 4; ++kc) {
        int w0 = kc * 32 + qd * 8;
        f16x8 ov0 = __builtin_bit_cast(f16x8, ovr[kc][0]);
        f16x8 ov1 = __builtin_bit_cast(f16x8, ovr[kc][1]);
        f16x8 ov2 = __builtin_bit_cast(f16x8, ovr[kc][2]);
        f16x8 ov3 = __builtin_bit_cast(f16x8, ovr[kc][3]);
        #pragma unroll
        for (int j = 0; j < 8; ++j) {
            int slot = hh * 128 + ((w0 + j + hh) & 127);
            f16x4t sc = *(const f16x4t*)&SclU[slot * 4];
            float v = (float)ov0[j] * (float)sc[0] + (float)ov1[j] * (float)sc[1]
                    + (float)ov2[j] * (float)sc[2] + (float)ov3[j] * (float)sc[3];
            af[kc][j] = (_Float16)v;
        }
    }

    f32x4 acc[4];
    #pragma unroll
    for (int nt = 0; nt < 4; ++nt) acc[nt] = (f32x4){0.f, 0.f, 0.f, 0.f};
    #pragma unroll
    for (int kc = 0; kc < 4; ++kc) {
        #pragma unroll
        for (int nt = 0; nt < 4; ++nt) {
            int o = o0 + nt * 16 + c;
            f16x8 bf = *(const f16x8*)&Fw[o * 128 + (((kc * 4 + qd) ^ c) * 8)];
            acc[nt] = __builtin_amdgcn_mfma_f32_16x16x32_f16(af[kc], bf, acc[nt], 0, 0, 0);
        }
    }

    float pa = prelu_a[0];
    float g  = bn_g[c0] * rsqrtf(bn_v[c0] + 1e-5f);
    float mn = bn_m[c0], bt = bn_b[c0];
    #pragma unroll
    for (int r = 0; r < 4; ++r) {
        int orow = rw + qd * 4 + r;
        #pragma unroll
        for (int nt = 0; nt < 4; ++nt) {
            int o = o0 + nt * 16 + c;
            float y = (acc[nt][r] + fc_b[o] - mn) * g + bt;
            y = y > 0.f ? y : pa * y;
            out[(size_t)orow * 128 + o] = y;
        }
    }
}

extern "C" void kernel_launch(void* const* d_in, const int* in_sizes, int n_in,
                              void* d_out, int out_size, void* d_ws, size_t ws_size,
                              hipStream_t stream) {
    const float* x     = (const float*)d_in[0];
    const float* wq    = (const float*)d_in[1];
    const float* bq    = (const float*)d_in[2];
    const float* wk    = (const float*)d_in[3];
    const float* bk    = (const float*)d_in[4];
    const float* wv    = (const float*)d_in[5];
    const float* bv    = (const float*)d_in[6];
    const float* fcw_f = (const float*)d_in[7];
    const float* fcb   = (const float*)d_in[8];
    const float* bn_g  = (const float*)d_in[9];
    const float* bn_b  = (const float*)d_in[10];
    const float* bn_m  = (const float*)d_in[11];
    const float* bn_v  = (const float*)d_in[12];
    const float* pa    = (const float*)d_in[13];
    float* out = (float*)d_out;

    unsigned short* Qp  = (unsigned short*)d_ws;
    unsigned short* Kp  = Qp + 8 * L_SZ * 64;
    unsigned short* Vp  = Kp + 8 * L_SZ * 64;
    unsigned short* Opart = Vp + 8 * L_SZ * 64;   // f16, 4*8*64*4096
    float* Mpart = (float*)(Opart + 4 * 8 * 64 * L_SZ);
    float* Lpart = Mpart + 4 * 8 * L_SZ;

    hipLaunchKernelGGL(qkv_kernel,  dim3(768),  dim3(256), 0, stream,
                       x, wq, wk, wv, bq, bk, bv, Qp, Kp, Vp);
    hipLaunchKernelGGL(attn_kernel, dim3(1024), dim3(256), 0, stream,
                       Qp, Kp, Vp, Opart, Mpart, Lpart);
    hipLaunchKernelGGL(fc_kernel,   dim3(512),  dim3(256), 0, stream,
                       Opart, Mpart, Lpart, fcw_f, fcb, bn_g, bn_b, bn_m, bn_v, pa, out);
}